// Round 1
// baseline (1211.579 us; speedup 1.0000x reference)
//
#include <hip/hip_runtime.h>
#include <math.h>

// SparseAttention: B=2 H=16 S=2048 D=128, local window half=102 (205 cols),
// outputs = (context [B,H,S,D], probs [B,H,S,S]) concatenated flat in d_out.
// Masked probs are exactly 0.0f (exp(-1e9 - m) underflows), so we write zeros.

namespace {
constexpr int Bc = 2, Hc = 16, Sc = 2048, Dc = 128;
constexpr int HALF = 102;            // int(2048*0.1) = 204; half = 102
constexpr int WIN  = 2 * HALF + 1;   // 205
constexpr float SCALE = 0.08838834764831845f;  // 1/sqrt(128)
}

__global__ __launch_bounds__(256) void sparse_attn_kernel(
    const float* __restrict__ Q, const float* __restrict__ Kp,
    const float* __restrict__ Vp, float* __restrict__ ctx,
    float* __restrict__ probs)
{
    const int row  = blockIdx.x;          // 0 .. B*H*S-1
    const int i    = row & (Sc - 1);
    const int bh   = row >> 11;           // log2(S) = 11
    const int tid  = threadIdx.x;
    const int lane = tid & 63;
    const int wave = tid >> 6;            // 0..3

    const int js = max(0, i - HALF);
    const int je = min(Sc - 1, i + HALF);
    const int count = je - js + 1;        // <= 205

    __shared__ float4 sq4[Dc / 4];        // query row, 128 floats
    __shared__ float  sp[WIN + 3];        // scores -> probs
    __shared__ float  red[256];           // softmax reductions
    __shared__ float4 sacc[256];          // context partial sums

    const size_t qoff = (size_t)row * Dc;
    if (tid < Dc / 4) sq4[tid] = ((const float4*)(Q + qoff))[tid];
    __syncthreads();

    // ---- Phase A: scores for the window (2 k-rows per wave per iter) ----
    {
        const float4* K4 = (const float4*)(Kp + (size_t)bh * Sc * Dc);
        const int sub = lane >> 5;        // which of the 2 rows
        const int sl  = lane & 31;        // 32 lanes cover D=128 as float4
        for (int jj = wave * 2; jj < count; jj += 8) {
            const int myjj = jj + sub;
            const bool valid = myjj < count;
            float partial = 0.f;
            if (valid) {
                const float4 k4 = K4[(size_t)(js + myjj) * (Dc / 4) + sl];
                const float4 q4 = sq4[sl];
                partial = q4.x * k4.x + q4.y * k4.y + q4.z * k4.z + q4.w * k4.w;
            }
            #pragma unroll
            for (int off = 16; off > 0; off >>= 1)
                partial += __shfl_down(partial, off, 32);
            if (sl == 0 && valid) sp[myjj] = partial * SCALE;
        }
    }
    __syncthreads();

    // ---- Phase B: softmax over the window ----
    const float myval = (tid < count) ? sp[tid] : -1e30f;
    red[tid] = myval;
    __syncthreads();
    #pragma unroll
    for (int s2 = 128; s2 > 0; s2 >>= 1) {
        if (tid < s2) red[tid] = fmaxf(red[tid], red[tid + s2]);
        __syncthreads();
    }
    const float m = red[0];
    __syncthreads();
    const float e = (tid < count) ? __expf(myval - m) : 0.f;
    red[tid] = e;
    __syncthreads();
    #pragma unroll
    for (int s2 = 128; s2 > 0; s2 >>= 1) {
        if (tid < s2) red[tid] += red[tid + s2];
        __syncthreads();
    }
    const float inv = 1.0f / red[0];
    if (tid < count) sp[tid] = e * inv;
    __syncthreads();

    // ---- Phase C: write full probs row (zeros outside window) ----
    {
        float4* prow4 = (float4*)(probs + (size_t)row * Sc);
        for (int c4 = tid; c4 < Sc / 4; c4 += 256) {
            const int c = c4 * 4;
            float4 o;
            o.x = (c + 0 >= js && c + 0 <= je) ? sp[c + 0 - js] : 0.f;
            o.y = (c + 1 >= js && c + 1 <= je) ? sp[c + 1 - js] : 0.f;
            o.z = (c + 2 >= js && c + 2 <= je) ? sp[c + 2 - js] : 0.f;
            o.w = (c + 3 >= js && c + 3 <= je) ? sp[c + 3 - js] : 0.f;
            prow4[c4] = o;
        }
    }

    // ---- Phase D: context = sum_j p_j * V[j,:]  (8-way split over j) ----
    {
        const float4* V4 = (const float4*)(Vp + (size_t)bh * Sc * Dc);
        const int d4   = tid & 31;        // 32 float4 = 128 floats of D
        const int part = tid >> 5;        // 0..7
        float4 acc = make_float4(0.f, 0.f, 0.f, 0.f);
        for (int jj = part; jj < count; jj += 8) {
            const float p = sp[jj];
            const float4 v4 = V4[(size_t)(js + jj) * (Dc / 4) + d4];
            acc.x += p * v4.x; acc.y += p * v4.y;
            acc.z += p * v4.z; acc.w += p * v4.w;
        }
        sacc[tid] = acc;
        __syncthreads();
        if (tid < 32) {
            float4 r = sacc[tid];
            #pragma unroll
            for (int pp = 1; pp < 8; ++pp) {
                const float4 o = sacc[tid + pp * 32];
                r.x += o.x; r.y += o.y; r.z += o.z; r.w += o.w;
            }
            ((float4*)(ctx + qoff))[tid] = r;
        }
    }
}

extern "C" void kernel_launch(void* const* d_in, const int* in_sizes, int n_in,
                              void* d_out, int out_size, void* d_ws, size_t ws_size,
                              hipStream_t stream) {
    const float* Q = (const float*)d_in[0];
    const float* K = (const float*)d_in[1];
    const float* V = (const float*)d_in[2];
    float* out   = (float*)d_out;
    float* ctx   = out;                                  // B*H*S*D floats
    float* probs = out + (size_t)Bc * Hc * Sc * Dc;      // B*H*S*S floats

    dim3 grid(Bc * Hc * Sc);   // one block per query row
    dim3 block(256);
    sparse_attn_kernel<<<grid, block, 0, stream>>>(Q, K, V, ctx, probs);
}

// Round 2
// 748.336 us; speedup vs baseline: 1.6190x; 1.6190x over previous
//
#include <hip/hip_runtime.h>
#include <math.h>

// SparseAttention B=2 H=16 S=2048 D=128, window half=102 (205 cols).
// out = ctx [B,H,S,D] ++ probs [B,H,S,S] (fp32).
// Round 2: MFMA bf16 QK^T (32 q-rows/block, 8 k-tiles of 32), vector fp32 PV,
// fused zero-fill issued first. Write-bound target ~140-240us.

namespace {
constexpr int Sc = 2048, Dc = 128;
constexpr int HALFW = 102;
constexpr float SCALE = 0.08838834764831845f;   // 1/sqrt(128)
constexpr int TQ  = 32;    // q rows per block
constexpr int CT  = 256;   // padded window cols (8 k-tiles of 32)
constexpr int KST = 136;   // bf16 row stride for Qs/Ks (272 B, 16B multiple)
constexpr int PST = 260;   // fp32 row stride for Ps (bank-friendly)
}

typedef __bf16 bf16x8 __attribute__((ext_vector_type(8)));
typedef float  f32x16 __attribute__((ext_vector_type(16)));

__device__ __forceinline__ unsigned short f2bf(float f) {
    unsigned u = __float_as_uint(f);
    u += 0x7fffu + ((u >> 16) & 1u);     // round-to-nearest-even
    return (unsigned short)(u >> 16);
}

__global__ __launch_bounds__(256, 2) void sparse_attn_mfma(
    const float* __restrict__ Q, const float* __restrict__ K,
    const float* __restrict__ V, float* __restrict__ ctx,
    float* __restrict__ probs)
{
    __shared__ __align__(16) unsigned short Qs[TQ * KST];        // 8704 B
    __shared__ __align__(16) unsigned char  Kbuf[128 * KST * 2]; // 34816 B (K bf16 / V fp32 chunks)
    __shared__ float Ps[TQ * PST];                                // 33280 B
    __shared__ float red[TQ][4];
    __shared__ float rowM[TQ];
    __shared__ float rowSinv[TQ];

    const int tid  = threadIdx.x;
    const int lane = tid & 63;
    const int w    = tid >> 6;         // wave 0..3
    const int lo   = lane & 31;
    const int hi   = lane >> 5;

    // XCD-aware swizzle: adjacent q-tiles on the same XCD (bx%8 heuristic)
    const int wid = (blockIdx.x & 7) * 256 + (blockIdx.x >> 3);
    const int bh  = wid >> 6;          // 0..31
    const int qt  = wid & 63;          // 0..63
    const int i0  = qt * TQ;
    const int js0 = max(0, i0 - HALFW);
    const int jend = min(js0 + CT, Sc);

    const size_t rowbase = (size_t)bh * Sc;
    float* probsBase = probs + (rowbase + i0) * (size_t)Sc;

    // ---------- Phase Z: zero-fill probs outside [js0, jend) ----------
    {
        const int headN = js0 & 3;                 // 0 or 2
        const int tailN = (4 - (jend & 3)) & 3;    // 0 or 2
        const int hn = headN + tailN;
        if (hn == 4) {
            int r = tid >> 2, s = tid & 3;
            if (r < TQ) {
                int col = (s < headN) ? (js0 - headN + s) : (jend + s - headN);
                probsBase[(size_t)r * Sc + col] = 0.0f;
            }
        } else if (hn == 2) {
            int r = tid >> 1, s = tid & 1;
            if (r < TQ) {
                int col = (s < headN) ? (js0 - headN + s) : (jend + s - headN);
                probsBase[(size_t)r * Sc + col] = 0.0f;
            }
        }
        const int leftQ   = (js0 - headN) >> 2;
        const int rightQ0 = (jend + tailN) >> 2;
        const float4 z4 = make_float4(0.f, 0.f, 0.f, 0.f);
        for (int r = 0; r < TQ; ++r) {
            float4* p4 = (float4*)(probsBase + (size_t)r * Sc);
            for (int c = tid; c < leftQ; c += 256) p4[c] = z4;
            for (int c = rightQ0 + tid; c < Sc / 4; c += 256) p4[c] = z4;
        }
    }

    // ---------- Stage Q (bf16) ----------
    {
        const float4* Q4 = (const float4*)(Q + (rowbase + i0) * Dc);
        #pragma unroll
        for (int it = 0; it < 4; ++it) {
            int idx = tid + 256 * it;              // 0..1023
            int r = idx >> 5, d4 = idx & 31;
            float4 q4 = Q4[r * 32 + d4];
            ushort4 b;
            b.x = f2bf(q4.x); b.y = f2bf(q4.y); b.z = f2bf(q4.z); b.w = f2bf(q4.w);
            *(ushort4*)&Qs[r * KST + d4 * 4] = b;
        }
    }

    unsigned short* Ks = (unsigned short*)Kbuf;
    const float4* K4 = (const float4*)(K + rowbase * Dc);
    const float4* V4 = (const float4*)(V + rowbase * Dc);

    // ---------- Scores: 2 chunks of 128 K-rows; wave w does k-tile (w) per chunk ----------
    f32x16 accE[2];
    #pragma unroll
    for (int ch = 0; ch < 2; ++ch) {
        #pragma unroll
        for (int it = 0; it < 16; ++it) {
            int idx = tid + 256 * it;              // 0..4095
            int r = idx >> 5, d4 = idx & 31;
            int jn = js0 + ch * 128 + r;
            if (jn > Sc - 1) jn = Sc - 1;          // clamp; masked later
            float4 k4 = K4[(size_t)jn * 32 + d4];
            ushort4 b;
            b.x = f2bf(k4.x); b.y = f2bf(k4.y); b.z = f2bf(k4.z); b.w = f2bf(k4.w);
            *(ushort4*)&Ks[r * KST + d4 * 4] = b;
        }
        __syncthreads();
        f32x16 acc;
        #pragma unroll
        for (int i = 0; i < 16; ++i) acc[i] = 0.0f;
        const unsigned short* qrow = &Qs[lo * KST + hi * 8];
        const unsigned short* krow = &Ks[(w * 32 + lo) * KST + hi * 8];
        #pragma unroll
        for (int dk = 0; dk < 8; ++dk) {
            bf16x8 a = *(const bf16x8*)(qrow + dk * 16);
            bf16x8 b = *(const bf16x8*)(krow + dk * 16);
            acc = __builtin_amdgcn_mfma_f32_32x32x16_bf16(a, b, acc, 0, 0, 0);
        }
        accE[ch] = acc;
        __syncthreads();   // before Ks is overwritten (next chunk / V)
    }

    // ---------- Mask + scale, row-max ----------
    const int cg0 = js0 + w * 32 + lo;
    {
        float mred[16];
        #pragma unroll
        for (int i = 0; i < 16; ++i) {
            int rl = (i & 3) + 8 * (i >> 2) + 4 * hi;
            int rg = i0 + rl;
            float m = -3.0e38f;
            #pragma unroll
            for (int ch = 0; ch < 2; ++ch) {
                int cg = cg0 + ch * 128;
                bool valid = (cg < Sc) & (cg >= rg - HALFW) & (cg <= rg + HALFW);
                float sv = valid ? accE[ch][i] * SCALE : -3.0e38f;
                accE[ch][i] = sv;
                m = fmaxf(m, sv);
            }
            mred[i] = m;
        }
        #pragma unroll
        for (int mk = 1; mk < 32; mk <<= 1) {
            #pragma unroll
            for (int i = 0; i < 16; ++i)
                mred[i] = fmaxf(mred[i], __shfl_xor(mred[i], mk, 64));
        }
        if (lo == 0) {
            #pragma unroll
            for (int i = 0; i < 16; ++i) {
                int rl = (i & 3) + 8 * (i >> 2) + 4 * hi;
                red[rl][w] = mred[i];
            }
        }
    }
    __syncthreads();
    if (tid < 128) {
        int rr = tid >> 2, sl = tid & 3;
        float v = red[rr][sl];
        v = fmaxf(v, __shfl_xor(v, 1, 64));
        v = fmaxf(v, __shfl_xor(v, 2, 64));
        if (sl == 0) rowM[rr] = v;
    }
    __syncthreads();

    // ---------- exp + row-sum ----------
    {
        float sred[16];
        #pragma unroll
        for (int i = 0; i < 16; ++i) {
            int rl = (i & 3) + 8 * (i >> 2) + 4 * hi;
            float rm = rowM[rl];
            float e0 = __expf(accE[0][i] - rm);   // masked (-3e38) underflows to exact 0
            float e1 = __expf(accE[1][i] - rm);
            accE[0][i] = e0; accE[1][i] = e1;
            sred[i] = e0 + e1;
        }
        #pragma unroll
        for (int mk = 1; mk < 32; mk <<= 1) {
            #pragma unroll
            for (int i = 0; i < 16; ++i)
                sred[i] += __shfl_xor(sred[i], mk, 64);
        }
        if (lo == 0) {
            #pragma unroll
            for (int i = 0; i < 16; ++i) {
                int rl = (i & 3) + 8 * (i >> 2) + 4 * hi;
                red[rl][w] = sred[i];
            }
        }
    }
    __syncthreads();
    if (tid < 128) {
        int rr = tid >> 2, sl = tid & 3;
        float v = red[rr][sl];
        v += __shfl_xor(v, 1, 64);
        v += __shfl_xor(v, 2, 64);
        if (sl == 0) rowSinv[rr] = 1.0f / v;
    }
    __syncthreads();

    // ---------- probs: global (coalesced, in-window) + Ps (LDS) ----------
    #pragma unroll
    for (int i = 0; i < 16; ++i) {
        int rl = (i & 3) + 8 * (i >> 2) + 4 * hi;
        float inv = rowSinv[rl];
        float* prow = probsBase + (size_t)rl * Sc;
        #pragma unroll
        for (int ch = 0; ch < 2; ++ch) {
            int cg = cg0 + ch * 128;
            float p = accE[ch][i] * inv;
            Ps[rl * PST + (cg - js0)] = p;
            if (cg < Sc) prow[cg] = p;
        }
    }
    __syncthreads();

    // ---------- PV: 4 chunks of 64 V-rows (fp32 in Kbuf), vector FMA ----------
    float4* Vsf = (float4*)Kbuf;                  // 64 x 32 float4 (32768 B)
    const int pr = tid >> 3;                      // row 0..31
    const int dg = tid & 7;                       // d-group 0..7 (16 floats each)
    float4 o0 = make_float4(0.f,0.f,0.f,0.f), o1 = o0, o2 = o0, o3 = o0;
    #pragma unroll
    for (int ch4 = 0; ch4 < 4; ++ch4) {
        #pragma unroll
        for (int it = 0; it < 8; ++it) {
            int idx = tid + 256 * it;             // 0..2047
            int r = idx >> 5, d4 = idx & 31;
            int jn = js0 + ch4 * 64 + r;
            if (jn > Sc - 1) jn = Sc - 1;         // p==0 there
            Vsf[r * 32 + d4] = V4[(size_t)jn * 32 + d4];
        }
        __syncthreads();
        const float* prow = &Ps[pr * PST + ch4 * 64];
        #pragma unroll 2
        for (int k = 0; k < 64; ++k) {
            float p = prow[k];
            const float4* vr = &Vsf[k * 32 + dg * 4];
            float4 v0 = vr[0], v1 = vr[1], v2 = vr[2], v3 = vr[3];
            o0.x = fmaf(p, v0.x, o0.x); o0.y = fmaf(p, v0.y, o0.y);
            o0.z = fmaf(p, v0.z, o0.z); o0.w = fmaf(p, v0.w, o0.w);
            o1.x = fmaf(p, v1.x, o1.x); o1.y = fmaf(p, v1.y, o1.y);
            o1.z = fmaf(p, v1.z, o1.z); o1.w = fmaf(p, v1.w, o1.w);
            o2.x = fmaf(p, v2.x, o2.x); o2.y = fmaf(p, v2.y, o2.y);
            o2.z = fmaf(p, v2.z, o2.z); o2.w = fmaf(p, v2.w, o2.w);
            o3.x = fmaf(p, v3.x, o3.x); o3.y = fmaf(p, v3.y, o3.y);
            o3.z = fmaf(p, v3.z, o3.z); o3.w = fmaf(p, v3.w, o3.w);
        }
        __syncthreads();
    }
    float4* C4 = (float4*)ctx + (rowbase + i0 + pr) * 32 + dg * 4;
    C4[0] = o0; C4[1] = o1; C4[2] = o2; C4[3] = o3;
}

extern "C" void kernel_launch(void* const* d_in, const int* in_sizes, int n_in,
                              void* d_out, int out_size, void* d_ws, size_t ws_size,
                              hipStream_t stream) {
    const float* Q = (const float*)d_in[0];
    const float* K = (const float*)d_in[1];
    const float* V = (const float*)d_in[2];
    float* out   = (float*)d_out;
    float* ctx   = out;                                   // 2*16*2048*128
    float* probs = out + (size_t)2 * 16 * 2048 * 128;     // 2*16*2048*2048

    dim3 grid(2 * 16 * (Sc / TQ));   // 2048 blocks
    dim3 block(256);
    sparse_attn_mfma<<<grid, block, 0, stream>>>(Q, K, V, ctx, probs);
}

// Round 3
// 692.901 us; speedup vs baseline: 1.7486x; 1.0800x over previous
//
#include <hip/hip_runtime.h>
#include <math.h>

// SparseAttention B=2 H=16 S=2048 D=128, window half=102 (205 cols).
// out = ctx [B,H,S,D] ++ probs [B,H,S,S] (fp32).
// Round 3: QK via bf16 MFMA (unchanged), PV restructured: 4 rows/thread +
// in-wave k-split-4 (shfl-reduced) reading P from transposed LDS (fp32) ->
// LDS traffic 8.6 GB -> 2.2 GB. Nontemporal stores for zero-fill/probs/ctx.

namespace {
constexpr int Sc = 2048, Dc = 128;
constexpr int HALFW = 102;
constexpr float SCALE = 0.08838834764831845f;   // 1/sqrt(128)
constexpr int TQ  = 32;    // q rows per block
constexpr int CT  = 256;   // padded window cols
constexpr int KST = 136;   // bf16 row stride for Qs/Ks
constexpr int VST = 132;   // fp32 row stride for Vsf (16B-aligned, kp-spread)
constexpr int PTS = 36;    // fp32 stride of Ps_t rows (per k): 32 rows + 4 pad
// LDS layout (bytes)
constexpr int OFF_KBUF = 0;                      // 34816: Ks bf16 128xKST / Vsf fp32 64xVST
constexpr int OFF_PST  = 34816;                  // 36864: Ps_t [256][36] fp32
constexpr int OFF_QS   = 34816;                  // Qs bf16 32xKST overlay (dead before Ps_t)
constexpr int OFF_RED  = 34816 + 36864;          // red[32][4] + rowM[32] + rowSinv[32]
constexpr int LDS_TOTAL = OFF_RED + 512 + 128 + 128;   // 72448 B -> 2 blocks/CU
}

typedef __bf16 bf16x8 __attribute__((ext_vector_type(8)));
typedef float  f32x16 __attribute__((ext_vector_type(16)));
typedef float  fx4    __attribute__((ext_vector_type(4)));

__device__ __forceinline__ unsigned short f2bf(float f) {
    unsigned u = __float_as_uint(f);
    u += 0x7fffu + ((u >> 16) & 1u);     // round-to-nearest-even
    return (unsigned short)(u >> 16);
}

__global__ __launch_bounds__(256, 2) void sparse_attn_mfma(
    const float* __restrict__ Q, const float* __restrict__ K,
    const float* __restrict__ V, float* __restrict__ ctx,
    float* __restrict__ probs)
{
    __shared__ __align__(16) unsigned char smem[LDS_TOTAL];
    unsigned short* Ks   = (unsigned short*)(smem + OFF_KBUF);
    float*          Vsf  = (float*)(smem + OFF_KBUF);
    float*          Ps_t = (float*)(smem + OFF_PST);
    unsigned short* Qs   = (unsigned short*)(smem + OFF_QS);
    float (*red)[4]      = (float(*)[4])(smem + OFF_RED);
    float* rowM          = (float*)(smem + OFF_RED + 512);
    float* rowSinv       = (float*)(smem + OFF_RED + 512 + 128);

    const int tid  = threadIdx.x;
    const int lane = tid & 63;
    const int w    = tid >> 6;         // wave 0..3
    const int lo   = lane & 31;
    const int hi   = lane >> 5;

    // XCD-aware swizzle: adjacent q-tiles on the same XCD
    const int wid = (blockIdx.x & 7) * 256 + (blockIdx.x >> 3);
    const int bh  = wid >> 6;          // 0..31
    const int qt  = wid & 63;          // 0..63
    const int i0  = qt * TQ;
    const int js0 = max(0, i0 - HALFW);
    const int jend = min(js0 + CT, Sc);

    const size_t rowbase = (size_t)bh * Sc;
    float* probsBase = probs + (rowbase + i0) * (size_t)Sc;

    // ---------- Phase Z: zero-fill probs outside [js0, jend) (nontemporal) ----------
    {
        const int headN = js0 & 3;                 // 0 or 2
        const int tailN = (4 - (jend & 3)) & 3;    // 0 or 2
        const int hn = headN + tailN;
        if (hn == 4) {
            int r = tid >> 2, s = tid & 3;
            if (r < TQ) {
                int col = (s < headN) ? (js0 - headN + s) : (jend + s - headN);
                __builtin_nontemporal_store(0.0f, probsBase + (size_t)r * Sc + col);
            }
        } else if (hn == 2) {
            int r = tid >> 1, s = tid & 1;
            if (r < TQ) {
                int col = (s < headN) ? (js0 - headN + s) : (jend + s - headN);
                __builtin_nontemporal_store(0.0f, probsBase + (size_t)r * Sc + col);
            }
        }
        const int leftQ   = (js0 - headN) >> 2;
        const int rightQ0 = (jend + tailN) >> 2;
        const fx4 z4 = {0.f, 0.f, 0.f, 0.f};
        for (int r = 0; r < TQ; ++r) {
            fx4* p4 = (fx4*)(probsBase + (size_t)r * Sc);
            for (int c = tid; c < leftQ; c += 256)
                __builtin_nontemporal_store(z4, p4 + c);
            for (int c = rightQ0 + tid; c < Sc / 4; c += 256)
                __builtin_nontemporal_store(z4, p4 + c);
        }
    }

    // ---------- Stage Q (bf16) ----------
    {
        const float4* Q4 = (const float4*)(Q + (rowbase + i0) * Dc);
        #pragma unroll
        for (int it = 0; it < 4; ++it) {
            int idx = tid + 256 * it;              // 0..1023
            int r = idx >> 5, d4 = idx & 31;
            float4 q4 = Q4[r * 32 + d4];
            ushort4 b;
            b.x = f2bf(q4.x); b.y = f2bf(q4.y); b.z = f2bf(q4.z); b.w = f2bf(q4.w);
            *(ushort4*)&Qs[r * KST + d4 * 4] = b;
        }
    }

    const float4* K4 = (const float4*)(K + rowbase * Dc);
    const float4* V4 = (const float4*)(V + rowbase * Dc);

    // ---------- Scores: 2 chunks of 128 K-rows; wave w does k-tile w per chunk ----------
    f32x16 accE[2];
    #pragma unroll
    for (int ch = 0; ch < 2; ++ch) {
        #pragma unroll
        for (int it = 0; it < 16; ++it) {
            int idx = tid + 256 * it;              // 0..4095
            int r = idx >> 5, d4 = idx & 31;
            int jn = js0 + ch * 128 + r;
            if (jn > Sc - 1) jn = Sc - 1;          // clamp; masked later
            float4 k4 = K4[(size_t)jn * 32 + d4];
            ushort4 b;
            b.x = f2bf(k4.x); b.y = f2bf(k4.y); b.z = f2bf(k4.z); b.w = f2bf(k4.w);
            *(ushort4*)&Ks[r * KST + d4 * 4] = b;
        }
        __syncthreads();
        f32x16 acc;
        #pragma unroll
        for (int i = 0; i < 16; ++i) acc[i] = 0.0f;
        const unsigned short* qrow = &Qs[lo * KST + hi * 8];
        const unsigned short* krow = &Ks[(w * 32 + lo) * KST + hi * 8];
        #pragma unroll
        for (int dk = 0; dk < 8; ++dk) {
            bf16x8 a = *(const bf16x8*)(qrow + dk * 16);
            bf16x8 b = *(const bf16x8*)(krow + dk * 16);
            acc = __builtin_amdgcn_mfma_f32_32x32x16_bf16(a, b, acc, 0, 0, 0);
        }
        accE[ch] = acc;
        __syncthreads();   // before Ks is overwritten
    }

    // ---------- Mask + scale, row-max ----------
    const int cg0 = js0 + w * 32 + lo;
    {
        float mred[16];
        #pragma unroll
        for (int i = 0; i < 16; ++i) {
            int rl = (i & 3) + 8 * (i >> 2) + 4 * hi;
            int rg = i0 + rl;
            float m = -3.0e38f;
            #pragma unroll
            for (int ch = 0; ch < 2; ++ch) {
                int cg = cg0 + ch * 128;
                bool valid = (cg < Sc) & (cg >= rg - HALFW) & (cg <= rg + HALFW);
                float sv = valid ? accE[ch][i] * SCALE : -3.0e38f;
                accE[ch][i] = sv;
                m = fmaxf(m, sv);
            }
            mred[i] = m;
        }
        #pragma unroll
        for (int mk = 1; mk < 32; mk <<= 1) {
            #pragma unroll
            for (int i = 0; i < 16; ++i)
                mred[i] = fmaxf(mred[i], __shfl_xor(mred[i], mk, 64));
        }
        if (lo == 0) {
            #pragma unroll
            for (int i = 0; i < 16; ++i) {
                int rl = (i & 3) + 8 * (i >> 2) + 4 * hi;
                red[rl][w] = mred[i];
            }
        }
    }
    __syncthreads();
    if (tid < 128) {
        int rr = tid >> 2, sl = tid & 3;
        float v = red[rr][sl];
        v = fmaxf(v, __shfl_xor(v, 1, 64));
        v = fmaxf(v, __shfl_xor(v, 2, 64));
        if (sl == 0) rowM[rr] = v;
    }
    __syncthreads();

    // ---------- exp + row-sum ----------
    {
        float sred[16];
        #pragma unroll
        for (int i = 0; i < 16; ++i) {
            int rl = (i & 3) + 8 * (i >> 2) + 4 * hi;
            float rm = rowM[rl];
            float e0 = __expf(accE[0][i] - rm);   // masked underflows to exact 0
            float e1 = __expf(accE[1][i] - rm);
            accE[0][i] = e0; accE[1][i] = e1;
            sred[i] = e0 + e1;
        }
        #pragma unroll
        for (int mk = 1; mk < 32; mk <<= 1) {
            #pragma unroll
            for (int i = 0; i < 16; ++i)
                sred[i] += __shfl_xor(sred[i], mk, 64);
        }
        if (lo == 0) {
            #pragma unroll
            for (int i = 0; i < 16; ++i) {
                int rl = (i & 3) + 8 * (i >> 2) + 4 * hi;
                red[rl][w] = sred[i];
            }
        }
    }
    __syncthreads();
    if (tid < 128) {
        int rr = tid >> 2, sl = tid & 3;
        float v = red[rr][sl];
        v += __shfl_xor(v, 1, 64);
        v += __shfl_xor(v, 2, 64);
        if (sl == 0) rowSinv[rr] = 1.0f / v;
    }
    __syncthreads();

    // ---------- probs: global in-window (NT) + transposed LDS Ps_t[k][row] ----------
    #pragma unroll
    for (int i = 0; i < 16; ++i) {
        int rl = (i & 3) + 8 * (i >> 2) + 4 * hi;
        float inv = rowSinv[rl];
        float* prow = probsBase + (size_t)rl * Sc;
        #pragma unroll
        for (int ch = 0; ch < 2; ++ch) {
            int cg = cg0 + ch * 128;
            float p = accE[ch][i] * inv;
            Ps_t[(cg - js0) * PTS + rl] = p;       // (cg-js0) in [0,256) always
            if (cg < Sc) __builtin_nontemporal_store(p, prow + cg);
        }
    }
    __syncthreads();

    // ---------- PV: 4 chunks of 64 V-rows (fp32 in Kbuf region) ----------
    // lane = rg(8: rows 4rg..4rg+3) x dgq(2: 16-float d-half) x kp(4: k%4)
    const int kp  = lane & 3;
    const int dgq = (lane >> 2) & 1;
    const int rg  = lane >> 3;
    fx4 o[4][4];
    #pragma unroll
    for (int c = 0; c < 4; ++c)
        #pragma unroll
        for (int j = 0; j < 4; ++j) o[c][j] = (fx4){0.f, 0.f, 0.f, 0.f};

    #pragma unroll
    for (int ch4 = 0; ch4 < 4; ++ch4) {
        #pragma unroll
        for (int it = 0; it < 8; ++it) {
            int idx = tid + 256 * it;             // 0..2047
            int r = idx >> 5, d4 = idx & 31;
            int jn = js0 + ch4 * 64 + r;
            if (jn > Sc - 1) jn = Sc - 1;         // p==0 there
            float4 v4g = V4[(size_t)jn * 32 + d4];
            *(float4*)&Vsf[r * VST + d4 * 4] = v4g;
        }
        __syncthreads();
        const float* Pbase = &Ps_t[(ch4 * 64) * PTS + 4 * rg];
        const float* Vbase = &Vsf[w * 32 + dgq * 16];
        #pragma unroll 4
        for (int kk = 0; kk < 16; ++kk) {
            int k = 4 * kk + kp;
            fx4 p4 = *(const fx4*)(Pbase + k * PTS);   // rows 4rg..4rg+3 at col k
            const float* vr = Vbase + k * VST;
            fx4 v0 = *(const fx4*)(vr);
            fx4 v1 = *(const fx4*)(vr + 4);
            fx4 v2 = *(const fx4*)(vr + 8);
            fx4 v3 = *(const fx4*)(vr + 12);
            #pragma unroll
            for (int c = 0; c < 4; ++c) {
                float pc = p4[c];
                o[c][0] += v0 * pc;
                o[c][1] += v1 * pc;
                o[c][2] += v2 * pc;
                o[c][3] += v3 * pc;
            }
        }
        __syncthreads();
    }

    // reduce over kp (lanes differing in bits 0..1) via shfl, then store
    #pragma unroll
    for (int c = 0; c < 4; ++c) {
        #pragma unroll
        for (int j = 0; j < 4; ++j) {
            fx4 t = o[c][j];
            #pragma unroll
            for (int comp = 0; comp < 4; ++comp) {
                float s = t[comp];
                s += __shfl_xor(s, 1, 64);
                s += __shfl_xor(s, 2, 64);
                t[comp] = s;
            }
            o[c][j] = t;
        }
    }
    if (kp == 0) {
        #pragma unroll
        for (int c = 0; c < 4; ++c) {
            float* crow = ctx + (rowbase + i0 + 4 * rg + c) * (size_t)Dc
                        + w * 32 + dgq * 16;
            #pragma unroll
            for (int j = 0; j < 4; ++j)
                __builtin_nontemporal_store(o[c][j], (fx4*)crow + j);
        }
    }
}

extern "C" void kernel_launch(void* const* d_in, const int* in_sizes, int n_in,
                              void* d_out, int out_size, void* d_ws, size_t ws_size,
                              hipStream_t stream) {
    const float* Q = (const float*)d_in[0];
    const float* K = (const float*)d_in[1];
    const float* V = (const float*)d_in[2];
    float* out   = (float*)d_out;
    float* ctx   = out;                                   // 2*16*2048*128
    float* probs = out + (size_t)2 * 16 * 2048 * 128;     // 2*16*2048*2048

    dim3 grid(2 * 16 * (Sc / TQ));   // 2048 blocks
    dim3 block(256);
    sparse_attn_mfma<<<grid, block, 0, stream>>>(Q, K, V, ctx, probs);
}